// Round 6
// baseline (127.361 us; speedup 1.0000x reference)
//
#include <hip/hip_runtime.h>
#include <hip/hip_bf16.h>

static constexpr int kC = 256;
static constexpr int kN = 1024;   // H*W

using s16x8 = __attribute__((ext_vector_type(8))) short;
using f32x4 = __attribute__((ext_vector_type(4))) float;

__device__ inline f32x4 mfma16(s16x8 a, s16x8 b, f32x4 c) {
  return __builtin_amdgcn_mfma_f32_16x16x32_bf16(a, b, c, 0, 0, 0);
}

__device__ inline unsigned short f2bf(float f) {   // RNE
  unsigned u = __builtin_bit_cast(unsigned, f);
  u = (u + 0x7fffu + ((u >> 16) & 1u)) >> 16;
  return (unsigned short)u;
}

__device__ inline float exp2_fast(float x) {   // 2^x, single v_exp_f32
  float r;
  asm("v_exp_f32 %0, %1" : "=v"(r) : "v"(x));
  return r;
}

__device__ inline unsigned cvt_pk_bf16(float lo, float hi) {
  unsigned r;
  asm("v_cvt_pk_bf16_f32 %0, %1, %2" : "=v"(r) : "v"(lo), "v"(hi));
  return r;
}

// 1/sqrt(64) * log2(e): folded into Q so QK^T lands in exp2 units.
static constexpr float kQScale = 0.18033688011112042f;

// Manual grid barrier: one arrival per block, agent-scope atomics + fences.
// Counter is memset to 0 at the head of every launch (deterministic replays).
__device__ inline void gbar(unsigned* ctr, unsigned target) {
  __syncthreads();
  if (threadIdx.x == 0) {
    __threadfence();   // release: flush this XCD's L2 (wbl2)
    __hip_atomic_fetch_add(ctr, 1u, __ATOMIC_ACQ_REL, __HIP_MEMORY_SCOPE_AGENT);
    unsigned v;
    do {
      __builtin_amdgcn_s_sleep(2);
      v = __hip_atomic_load(ctr, __ATOMIC_ACQUIRE, __HIP_MEMORY_SCOPE_AGENT);
    } while (v < target);
    __threadfence();   // acquire: invalidate stale L1/L2 lines on this CU/XCD
  }
  __syncthreads();
}

// ---------------------------------------------------------------------------
// 64x64 (K=256) MFMA tile helpers: per wave 32m x 32n, acc[2][2], frag dbuf.
// ---------------------------------------------------------------------------
__device__ inline void gload2(const s16x8* __restrict__ Af,
                              const s16x8* __restrict__ Bf,
                              int Mt0, int Nt0, int kt, int lane,
                              s16x8 (&a)[2], s16x8 (&bb)[2]) {
#pragma unroll
  for (int mt = 0; mt < 2; ++mt)
    a[mt] = Af[((size_t)(Mt0 + mt) * 8 + kt) * 64 + lane];
#pragma unroll
  for (int nt = 0; nt < 2; ++nt)
    bb[nt] = Bf[((size_t)(Nt0 + nt) * 8 + kt) * 64 + lane];
}

__device__ inline void gmfma2(const s16x8 (&a)[2], const s16x8 (&bb)[2],
                              f32x4 (&acc)[2][2], bool swap) {
  if (swap) {
#pragma unroll
    for (int mt = 0; mt < 2; ++mt)
#pragma unroll
      for (int nt = 0; nt < 2; ++nt)
        acc[mt][nt] = mfma16(bb[nt], a[mt], acc[mt][nt]);
  } else {
#pragma unroll
    for (int mt = 0; mt < 2; ++mt)
#pragma unroll
      for (int nt = 0; nt < 2; ++nt)
        acc[mt][nt] = mfma16(a[mt], bb[nt], acc[mt][nt]);
  }
}

__device__ inline void ktile_dbuf(const s16x8* __restrict__ Af,
                                  const s16x8* __restrict__ Bf,
                                  int Mt0, int Nt0, int lane, bool swap,
                                  f32x4 (&acc)[2][2]) {
  s16x8 aA[2], bA[2], aB[2], bB[2];
  gload2(Af, Bf, Mt0, Nt0, 0, lane, aA, bA);
#pragma unroll
  for (int kt = 0; kt < 8; kt += 2) {
    gload2(Af, Bf, Mt0, Nt0, kt + 1, lane, aB, bB);
    gmfma2(aA, bA, acc, swap);
    if (kt + 2 < 8) gload2(Af, Bf, Mt0, Nt0, kt + 2, lane, aA, bA);
    gmfma2(aB, bB, acc, swap);
  }
}

// ---------------------------------------------------------------------------
// Fused megakernel, 256 blocks x 512 threads (two 256-thread sub-blocks).
// Virtual work id: wid = xcd*64 + (bid>>3)*2 + sub  (0..511), xcd = bid&7.
// Phases (manual grid barrier between): A GN+pack, B QKV GEMM, C attn, D proj.
// All bulk tensors chain XCD-locally (batch b = xcd in every phase).
// ---------------------------------------------------------------------------
__global__ __launch_bounds__(512) void fused_kernel(
    const float* __restrict__ x, const float* __restrict__ gamma,
    const float* __restrict__ beta,
    const float* __restrict__ wq, const float* __restrict__ bq,
    const float* __restrict__ wpj, const float* __restrict__ bpj,
    float* __restrict__ out,
    unsigned short* __restrict__ Wqp, unsigned short* __restrict__ Wpp,
    unsigned short* __restrict__ hTp, unsigned short* __restrict__ Qp,
    unsigned short* __restrict__ Kp, unsigned short* __restrict__ Vp,
    unsigned short* __restrict__ aoTp, unsigned* __restrict__ ctr) {
  const int bid = blockIdx.x;        // 0..255
  const int t = threadIdx.x;         // 0..511
  const int sub = t >> 8;            // sub-block 0/1
  const int st = t & 255;            // thread within sub-block
  const int w8 = t >> 6;             // wave 0..7 (P_lds index)
  const int wave = w8 & 3;           // wave within sub-block
  const int lane = t & 63;
  const int li = lane & 15, grp = lane >> 4;
  const int wm = wave >> 1, wn = wave & 1;
  const int xcd = bid & 7;
  const int vb = (bid >> 3) * 2 + sub;   // 0..63 within xcd

  __shared__ __align__(16) unsigned short P_lds[8][16][56];
  __shared__ float rs[4], rss[4];

  // ============ Phase A: GN (sub 0) + weight pack (sub 1) ============
  float gn_vv[8][4];
  float gn_s = 0.f, gn_ss = 0.f;
  const int gn_b = xcd, gn_g = bid >> 3;
  if (sub == 0) {
    const size_t base = ((size_t)gn_b * kC + (size_t)gn_g * 8) * kN;
    const float4* __restrict__ x4 = (const float4*)(x + base);
#pragma unroll
    for (int i = 0; i < 8; ++i) {
      const float4 v = x4[st + 256 * i];
      gn_vv[i][0] = v.x; gn_vv[i][1] = v.y; gn_vv[i][2] = v.z; gn_vv[i][3] = v.w;
      gn_s += v.x + v.y + v.z + v.w;
      gn_ss += v.x * v.x + v.y * v.y + v.z * v.z + v.w * v.w;
    }
#pragma unroll
    for (int off = 32; off > 0; off >>= 1) {
      gn_s += __shfl_xor(gn_s, off);
      gn_ss += __shfl_xor(gn_ss, off);
    }
    if (lane == 0) { rs[wave] = gn_s; rss[wave] = gn_ss; }
  } else {
    // weight pack: unit u = xcd*32 + (bid>>3) in [0,256); 128 ids each.
    if (st < 128) {
      const int id = (xcd * 32 + (bid >> 3)) * 128 + st;   // 0..32767
      const float* src;
      unsigned short* dst;
      if (id < 24576) {
        const int fragid = id >> 6, ln = id & 63;
        const int Mt = fragid >> 3, kt = fragid & 7;
        src = wq + (size_t)(Mt * 16 + (ln & 15)) * 256 + kt * 32 + (ln >> 4) * 8;
        dst = Wqp + (size_t)id * 8;
      } else {
        const int id2 = id - 24576;
        const int fragid = id2 >> 6, ln = id2 & 63;
        const int Mt = fragid >> 3, kt = fragid & 7;
        src = wpj + (size_t)(Mt * 16 + (ln & 15)) * 256 + kt * 32 + (ln >> 4) * 8;
        dst = Wpp + (size_t)id2 * 8;
      }
      const float4 f0 = *(const float4*)src;
      const float4 f1 = *(const float4*)(src + 4);
      ushort4 o0, o1;
      o0.x = f2bf(f0.x); o0.y = f2bf(f0.y); o0.z = f2bf(f0.z); o0.w = f2bf(f0.w);
      o1.x = f2bf(f1.x); o1.y = f2bf(f1.y); o1.z = f2bf(f1.z); o1.w = f2bf(f1.w);
      *(ushort4*)dst = o0;
      *(ushort4*)(dst + 4) = o1;
    }
  }
  __syncthreads();
  if (sub == 0) {
    const float s = rs[0] + rs[1] + rs[2] + rs[3];
    const float ss = rss[0] + rss[1] + rss[2] + rss[3];
    const float mean = s * (1.f / 8192.f);
    const float var = ss * (1.f / 8192.f) - mean * mean;
    const float rinv = rsqrtf(var + 1e-5f);
    float ga[8], be[8];
#pragma unroll
    for (int i = 0; i < 8; ++i) {
      ga[i] = gamma[gn_g * 8 + i] * rinv;
      be[i] = beta[gn_g * 8 + i] - mean * ga[i];
    }
    const int kt = gn_g >> 2, gq = gn_g & 3;
#pragma unroll
    for (int r = 0; r < 4; ++r) {
      const int pos = 4 * st + r;
      const int nt = pos >> 4, lp = pos & 15;
      unsigned short* dst =
          hTp + ((size_t)((gn_b * 64 + nt) * 8 + kt) * 64 + (gq * 16 + lp)) * 8;
      ushort4 o0, o1;
      o0.x = f2bf(gn_vv[0][r] * ga[0] + be[0]);
      o0.y = f2bf(gn_vv[1][r] * ga[1] + be[1]);
      o0.z = f2bf(gn_vv[2][r] * ga[2] + be[2]);
      o0.w = f2bf(gn_vv[3][r] * ga[3] + be[3]);
      o1.x = f2bf(gn_vv[4][r] * ga[4] + be[4]);
      o1.y = f2bf(gn_vv[5][r] * ga[5] + be[5]);
      o1.z = f2bf(gn_vv[6][r] * ga[6] + be[6]);
      o1.w = f2bf(gn_vv[7][r] * ga[7] + be[7]);
      *(ushort4*)dst = o0;
      *(ushort4*)(dst + 4) = o1;
    }
  }
  gbar(ctr, 256);

  // ============ Phase B: QKV GEMM (1536 tiles, 3 per sub-block) ============
  {
    const int b = xcd;
    const s16x8* __restrict__ Af = (const s16x8*)Wqp;
    const s16x8* __restrict__ Bf = (const s16x8*)hTp;
#pragma unroll 1
    for (int p = 0; p < 3; ++p) {
      const int r = p * 64 + vb;             // 0..191 within batch
      const int mb = r >> 4, nb = r & 15;    // mb 0..11
      const int m0 = mb * 64 + wm * 32;
      const int n0 = nb * 64 + wn * 32;
      const int Mt0 = m0 >> 4;
      const int Nt0 = b * 64 + (n0 >> 4);
      const bool swap = mb >= 8;             // V tiles
      f32x4 acc[2][2];
#pragma unroll
      for (int mt = 0; mt < 2; ++mt)
#pragma unroll
        for (int nt = 0; nt < 2; ++nt) acc[mt][nt] = f32x4{0.f, 0.f, 0.f, 0.f};
      ktile_dbuf(Af, Bf, Mt0, Nt0, lane, swap, acc);

      if (!swap) {
        // Q/K: D rows = ch (4grp+r), cols = pos (li); Q gets kQScale.
        unsigned short* __restrict__ Tp = (mb < 4) ? Qp : Kp;
        const float qs = (mb < 4) ? kQScale : 1.0f;
#pragma unroll
        for (int mt = 0; mt < 2; ++mt) {
          const int mbase = m0 + mt * 16;
          const int head = (mbase >> 6) & 3;
          const int bh = b * 4 + head;
          const int c16 = mbase & 63;
          const int ks = c16 >> 5;
          const int grpp = ((c16 >> 3) + (grp >> 1)) & 3;
          const float4 bv = *(const float4*)(bq + mbase + 4 * grp);
#pragma unroll
          for (int nt = 0; nt < 2; ++nt) {
            const int pt = (n0 >> 4) + nt;
            ushort4 o;
            o.x = f2bf((acc[mt][nt][0] + bv.x) * qs);
            o.y = f2bf((acc[mt][nt][1] + bv.y) * qs);
            o.z = f2bf((acc[mt][nt][2] + bv.z) * qs);
            o.w = f2bf((acc[mt][nt][3] + bv.w) * qs);
            *(ushort4*)(Tp + (size_t)bh * 65536 +
                        ((size_t)(pt * 2 + ks) * 64 + grpp * 16 + li) * 8 +
                        (grp & 1) * 4) = o;
          }
        }
      } else {
        // V: D rows = pos (4grp+r), cols = ch (li).
#pragma unroll
        for (int mt = 0; mt < 2; ++mt) {
          const int mbase = m0 + mt * 16;
          const int head = (mbase >> 6) & 3;
          const int bh = b * 4 + head;
          const int ct = (mbase & 63) >> 4;
          const float bvc = bq[mbase + li];
          const int kvt = n0 >> 5;
#pragma unroll
          for (int nt = 0; nt < 2; ++nt) {
            const int grpv = (nt * 2 + (grp >> 1)) & 3;
            ushort4 o;
            o.x = f2bf(acc[mt][nt][0] + bvc);
            o.y = f2bf(acc[mt][nt][1] + bvc);
            o.z = f2bf(acc[mt][nt][2] + bvc);
            o.w = f2bf(acc[mt][nt][3] + bvc);
            *(ushort4*)(Vp + (size_t)bh * 65536 +
                        ((size_t)(ct * 32 + kvt) * 64 + grpv * 16 + li) * 8 +
                        (grp & 1) * 4) = o;
          }
        }
      }
    }
  }
  gbar(ctr, 512);

  // ============ Phase C: flash attention (512 tiles, 1 per sub-block) ====
  {
    const int swz = xcd * 64 + vb;
    const int bh = swz >> 4, qb = swz & 15;
    const int b = bh >> 2, head = bh & 3;
    const int q0 = qb * 64 + wave * 16;
    const unsigned short* __restrict__ Qb = Qp + (size_t)bh * 65536;
    const unsigned short* __restrict__ Kb = Kp + (size_t)bh * 65536;
    const unsigned short* __restrict__ Vb = Vp + (size_t)bh * 65536;

    s16x8 qf[2];
#pragma unroll
    for (int ks = 0; ks < 2; ++ks)
      qf[ks] = *(const s16x8*)(Qb + (((q0 >> 4) * 2 + ks) * 64 + lane) * 8);

    f32x4 O[4];
#pragma unroll
    for (int ct = 0; ct < 4; ++ct) O[ct] = f32x4{0.f, 0.f, 0.f, 0.f};
    f32x4 lvec = f32x4{0.f, 0.f, 0.f, 0.f};
    float m_run = -1.0e30f;

    s16x8 ka[2][2], kb2[2][2];
#pragma unroll
    for (int mt = 0; mt < 2; ++mt)
#pragma unroll
      for (int ks = 0; ks < 2; ++ks)
        ka[mt][ks] = *(const s16x8*)(Kb + ((size_t)(mt * 2 + ks) * 64 + lane) * 8);

    auto body = [&](int it, s16x8 (&kc)[2][2], s16x8 (&kn)[2][2]) {
      s16x8 vf[4];
#pragma unroll
      for (int ct = 0; ct < 4; ++ct)
        vf[ct] = *(const s16x8*)(Vb + ((size_t)(ct * 32 + it) * 64 + lane) * 8);
      // prefetch next K tile (it=31 overreads into Vp region: allocated)
#pragma unroll
      for (int mt = 0; mt < 2; ++mt)
#pragma unroll
        for (int ks = 0; ks < 2; ++ks)
          kn[mt][ks] = *(const s16x8*)(
              Kb + ((size_t)(((it + 1) * 2 + mt) * 2 + ks) * 64 + lane) * 8);
      // S^T (rows j = 16mt+4grp+r, col q = li), exp2 units
      f32x4 s[2];
#pragma unroll
      for (int mt = 0; mt < 2; ++mt) {
        s[mt] = mfma16(kc[mt][0], qf[0], f32x4{0.f, 0.f, 0.f, 0.f});
        s[mt] = mfma16(kc[mt][1], qf[1], s[mt]);
      }
      const float A = fmaxf(fmaxf(s[0][0], s[0][1]), s[0][2]);
      const float B = fmaxf(fmaxf(s[0][3], s[1][0]), s[1][1]);
      const float C = fmaxf(fmaxf(s[1][2], s[1][3]), A);
      float pm = fmaxf(B, C);
      pm = fmaxf(pm, __shfl_xor(pm, 16));
      pm = fmaxf(pm, __shfl_xor(pm, 32));
      if (!__all(pm <= m_run + 8.0f)) {   // defer-max rescale
        const float mnew = fmaxf(m_run, pm);
        const float f = exp2_fast(m_run - mnew);
        m_run = mnew;
        lvec *= f;
#pragma unroll
        for (int ct = 0; ct < 4; ++ct) O[ct] *= f;
      }
      f32x4 p[2];
#pragma unroll
      for (int mt = 0; mt < 2; ++mt) {
#pragma unroll
        for (int r = 0; r < 4; ++r) p[mt][r] = exp2_fast(s[mt][r] - m_run);
        lvec += p[mt];
      }
#pragma unroll
      for (int mt = 0; mt < 2; ++mt) {
        uint2 cc;
        cc.x = cvt_pk_bf16(p[mt][0], p[mt][1]);
        cc.y = cvt_pk_bf16(p[mt][2], p[mt][3]);
        *(uint2*)&P_lds[w8][li][16 * mt + 4 * grp] = cc;
      }
      const s16x8 pf = *(const s16x8*)&P_lds[w8][li][8 * grp];
#pragma unroll
      for (int ct = 0; ct < 4; ++ct) O[ct] = mfma16(vf[ct], pf, O[ct]);
    };

#pragma unroll 1
    for (int h2 = 0; h2 < 16; ++h2) {
      body(2 * h2, ka, kb2);
      body(2 * h2 + 1, kb2, ka);
    }

    float lt = lvec[0] + lvec[1] + lvec[2] + lvec[3];
    lt += __shfl_xor(lt, 16);
    lt += __shfl_xor(lt, 32);
    const float rinv = 1.f / lt;
#pragma unroll
    for (int ct = 0; ct < 4; ++ct) {
      const int ktp = head * 2 + (ct >> 1);
      const int grpp = ((ct & 1) * 2 + (grp >> 1)) & 3;
      ushort4 o;
      o.x = f2bf(O[ct][0] * rinv);
      o.y = f2bf(O[ct][1] * rinv);
      o.z = f2bf(O[ct][2] * rinv);
      o.w = f2bf(O[ct][3] * rinv);
      *(ushort4*)(aoTp +
                  ((size_t)((b * 64 + (q0 >> 4)) * 8 + ktp) * 64 + grpp * 16 + li) * 8 +
                  (grp & 1) * 4) = o;
    }
  }
  gbar(ctr, 768);

  // ============ Phase D: proj GEMM (512 tiles, 1 per sub-block) ============
  {
    const int idx = xcd * 64 + vb;
    const int b = idx >> 6, rr2 = idx & 63;
    const int mb = rr2 >> 4, nb = rr2 & 15;   // mb 0..3
    const int m0 = mb * 64 + wm * 32;
    const int n0 = nb * 64 + wn * 32;
    const int Mt0 = m0 >> 4;
    const int Nt0 = b * 64 + (n0 >> 4);
    const s16x8* __restrict__ Af = (const s16x8*)Wpp;
    const s16x8* __restrict__ Bf = (const s16x8*)aoTp;
    f32x4 acc[2][2];
#pragma unroll
    for (int mt = 0; mt < 2; ++mt)
#pragma unroll
      for (int nt = 0; nt < 2; ++nt) acc[mt][nt] = f32x4{0.f, 0.f, 0.f, 0.f};
    ktile_dbuf(Af, Bf, Mt0, Nt0, lane, false, acc);

#pragma unroll
    for (int mt = 0; mt < 2; ++mt) {
      const int mbase = m0 + mt * 16 + 4 * grp;
      const float4 bv = *(const float4*)(bpj + mbase);
      const float bvr[4] = {bv.x, bv.y, bv.z, bv.w};
#pragma unroll
      for (int nt = 0; nt < 2; ++nt) {
        const int pos = n0 + nt * 16 + li;
#pragma unroll
        for (int r2 = 0; r2 < 4; ++r2) {
          const size_t ob = ((size_t)(b * 256 + mbase + r2)) * 1024 + pos;
          out[ob] = acc[mt][nt][r2] + bvr[r2] + x[ob];
        }
      }
    }
  }
}

// ---------------------------------------------------------------------------
extern "C" void kernel_launch(void* const* d_in, const int* in_sizes, int n_in,
                              void* d_out, int out_size, void* d_ws, size_t ws_size,
                              hipStream_t stream) {
  const float* x      = (const float*)d_in[0];
  const float* gamma  = (const float*)d_in[1];
  const float* beta   = (const float*)d_in[2];
  const float* w_qkv  = (const float*)d_in[3];
  const float* b_qkv  = (const float*)d_in[4];
  const float* w_proj = (const float*)d_in[5];
  const float* b_proj = (const float*)d_in[6];
  float* out = (float*)d_out;

  unsigned short* ws = (unsigned short*)d_ws;
  unsigned short* Wqp  = ws;                    // 196608
  unsigned short* Wpp  = Wqp + 196608;          // 65536
  unsigned short* hTp  = Wpp + 65536;           // 2097152
  unsigned short* Qp   = hTp + 2097152;         // 2097152
  unsigned short* Kp   = Qp + 2097152;          // 2097152
  unsigned short* Vp   = Kp + 2097152;          // 2097152
  unsigned short* aoTp = Vp + 2097152;          // 2097152
  unsigned* ctr = (unsigned*)(aoTp + 2097152);  // 4 bytes

  hipMemsetAsync(ctr, 0, sizeof(unsigned), stream);
  hipLaunchKernelGGL(fused_kernel, dim3(256), dim3(512), 0, stream,
                     x, gamma, beta, w_qkv, b_qkv, w_proj, b_proj, out,
                     Wqp, Wpp, hTp, Qp, Kp, Vp, aoTp, ctr);
}

// Round 7
// 43.063 us; speedup vs baseline: 2.9575x; 2.9575x over previous
//
#include <hip/hip_runtime.h>
#include <hip/hip_bf16.h>

static constexpr int kC = 256;
static constexpr int kN = 1024;   // H*W

using s16x8 = __attribute__((ext_vector_type(8))) short;
using f32x4 = __attribute__((ext_vector_type(4))) float;

__device__ inline f32x4 mfma16(s16x8 a, s16x8 b, f32x4 c) {
  return __builtin_amdgcn_mfma_f32_16x16x32_bf16(a, b, c, 0, 0, 0);
}

__device__ inline unsigned short f2bf(float f) {   // RNE
  unsigned u = __builtin_bit_cast(unsigned, f);
  u = (u + 0x7fffu + ((u >> 16) & 1u)) >> 16;
  return (unsigned short)u;
}

__device__ inline float exp2_fast(float x) {   // 2^x, single v_exp_f32
  float r;
  asm("v_exp_f32 %0, %1" : "=v"(r) : "v"(x));
  return r;
}

__device__ inline unsigned cvt_pk_bf16(float lo, float hi) {
  unsigned r;
  asm("v_cvt_pk_bf16_f32 %0, %1, %2" : "=v"(r) : "v"(lo), "v"(hi));
  return r;
}

// 1/sqrt(64) * log2(e): folded into Q so QK^T lands in exp2 units.
static constexpr float kQScale = 0.18033688011112042f;

// ---------------------------------------------------------------------------
// prep: blocks 0..127 pack weights into A-frag layout; blocks 128..383 GN.
// ---------------------------------------------------------------------------
__global__ __launch_bounds__(256) void prep_kernel(
    const float* __restrict__ x, const float* __restrict__ gamma,
    const float* __restrict__ beta, unsigned short* __restrict__ hTp,
    const float* __restrict__ wq, const float* __restrict__ wp,
    unsigned short* __restrict__ Wqp, unsigned short* __restrict__ Wpp) {
  if (blockIdx.x < 128) {
    const int tid = blockIdx.x * 256 + threadIdx.x;   // 0..32767
    const float* src;
    unsigned short* dst;
    if (tid < 24576) {
      const int fragid = tid >> 6, lane = tid & 63;
      const int Mt = fragid >> 3, kt = fragid & 7;
      src = wq + (size_t)(Mt * 16 + (lane & 15)) * 256 + kt * 32 + (lane >> 4) * 8;
      dst = Wqp + (size_t)tid * 8;
    } else {
      const int id = tid - 24576;
      const int fragid = id >> 6, lane = id & 63;
      const int Mt = fragid >> 3, kt = fragid & 7;
      src = wp + (size_t)(Mt * 16 + (lane & 15)) * 256 + kt * 32 + (lane >> 4) * 8;
      dst = Wpp + (size_t)id * 8;
    }
    const float4 f0 = *(const float4*)src;
    const float4 f1 = *(const float4*)(src + 4);
    ushort4 o0, o1;
    o0.x = f2bf(f0.x); o0.y = f2bf(f0.y); o0.z = f2bf(f0.z); o0.w = f2bf(f0.w);
    o1.x = f2bf(f1.x); o1.y = f2bf(f1.y); o1.z = f2bf(f1.z); o1.w = f2bf(f1.w);
    *(ushort4*)dst = o0;
    *(ushort4*)(dst + 4) = o1;
    return;
  }

  const int bg = blockIdx.x - 128;
  const int b = bg >> 5, g = bg & 31;
  const size_t base = ((size_t)b * kC + (size_t)g * 8) * kN;
  const float4* __restrict__ x4 = (const float4*)(x + base);
  const int t = threadIdx.x;

  float vv[8][4];
  float s = 0.f, ss = 0.f;
#pragma unroll
  for (int i = 0; i < 8; ++i) {
    const float4 v = x4[t + 256 * i];
    vv[i][0] = v.x; vv[i][1] = v.y; vv[i][2] = v.z; vv[i][3] = v.w;
    s += v.x + v.y + v.z + v.w;
    ss += v.x * v.x + v.y * v.y + v.z * v.z + v.w * v.w;
  }
#pragma unroll
  for (int off = 32; off > 0; off >>= 1) {
    s += __shfl_xor(s, off);
    ss += __shfl_xor(ss, off);
  }
  __shared__ float rs[4], rss[4];
  const int wave = t >> 6, lane = t & 63;
  if (lane == 0) { rs[wave] = s; rss[wave] = ss; }
  __syncthreads();
  s = rs[0] + rs[1] + rs[2] + rs[3];
  ss = rss[0] + rss[1] + rss[2] + rss[3];
  const float mean = s * (1.f / 8192.f);
  const float var = ss * (1.f / 8192.f) - mean * mean;
  const float rinv = rsqrtf(var + 1e-5f);
  float ga[8], be[8];
#pragma unroll
  for (int i = 0; i < 8; ++i) {
    ga[i] = gamma[g * 8 + i] * rinv;
    be[i] = beta[g * 8 + i] - mean * ga[i];
  }
  const int kt = g >> 2, gq = g & 3;
#pragma unroll
  for (int r = 0; r < 4; ++r) {
    const int pos = 4 * t + r;
    const int nt = pos >> 4, lp = pos & 15;
    unsigned short* dst =
        hTp + ((size_t)((b * 64 + nt) * 8 + kt) * 64 + (gq * 16 + lp)) * 8;
    ushort4 o0, o1;
    o0.x = f2bf(vv[0][r] * ga[0] + be[0]);
    o0.y = f2bf(vv[1][r] * ga[1] + be[1]);
    o0.z = f2bf(vv[2][r] * ga[2] + be[2]);
    o0.w = f2bf(vv[3][r] * ga[3] + be[3]);
    o1.x = f2bf(vv[4][r] * ga[4] + be[4]);
    o1.y = f2bf(vv[5][r] * ga[5] + be[5]);
    o1.z = f2bf(vv[6][r] * ga[6] + be[6]);
    o1.w = f2bf(vv[7][r] * ga[7] + be[7]);
    *(ushort4*)dst = o0;
    *(ushort4*)(dst + 4) = o1;
  }
}

// ---------------------------------------------------------------------------
// LDS-free bf16 MFMA GEMM, depth-2 register prefetch (3 rotating slots).
// Block: 4 waves (2m x 2n), tile 128m x 64n; wave 64m x 32n; K=256.
// ---------------------------------------------------------------------------
__device__ inline void gload(const s16x8* __restrict__ Af,
                             const s16x8* __restrict__ Bf,
                             int Mt0, int Nt0, int kt, int lane,
                             s16x8 (&a)[4], s16x8 (&bb)[2]) {
#pragma unroll
  for (int mt = 0; mt < 4; ++mt)
    a[mt] = Af[((size_t)(Mt0 + mt) * 8 + kt) * 64 + lane];
#pragma unroll
  for (int nt = 0; nt < 2; ++nt)
    bb[nt] = Bf[((size_t)(Nt0 + nt) * 8 + kt) * 64 + lane];
}

__device__ inline void gmfma(const s16x8 (&a)[4], const s16x8 (&bb)[2],
                             f32x4 (&acc)[4][2], bool swap) {
  if (swap) {
#pragma unroll
    for (int mt = 0; mt < 4; ++mt)
#pragma unroll
      for (int nt = 0; nt < 2; ++nt)
        acc[mt][nt] = mfma16(bb[nt], a[mt], acc[mt][nt]);
  } else {
#pragma unroll
    for (int mt = 0; mt < 4; ++mt)
#pragma unroll
      for (int nt = 0; nt < 2; ++nt)
        acc[mt][nt] = mfma16(a[mt], bb[nt], acc[mt][nt]);
  }
}

template <int MT128, bool PROJ>
__global__ __launch_bounds__(256) void gemm_pk_kernel(
    const unsigned short* __restrict__ Wp, const float* __restrict__ bias,
    const unsigned short* __restrict__ Bp,
    unsigned short* __restrict__ Qp, unsigned short* __restrict__ Kp,
    unsigned short* __restrict__ Vp,
    const float* __restrict__ res, float* __restrict__ outp) {
  constexpr int CPX = MT128 * 16;
  const int bid = blockIdx.x;
  const int swz = (bid & 7) * CPX + (bid >> 3);
  const int b = swz / CPX, rr = swz % CPX;
  const int mb = rr >> 4, nb = rr & 15;
  const int t = threadIdx.x;
  const int wave = t >> 6, lane = t & 63;
  const int li = lane & 15, grp = lane >> 4;
  const int m0 = mb * 128 + (wave >> 1) * 64;
  const int n0 = nb * 64 + (wave & 1) * 32;
  const bool swap = (!PROJ) && (mb >= 4);
  const int Mt0 = m0 >> 4;
  const int Nt0 = b * 64 + (n0 >> 4);
  const s16x8* __restrict__ Af = (const s16x8*)Wp;
  const s16x8* __restrict__ Bf = (const s16x8*)Bp;

  f32x4 acc[4][2];
#pragma unroll
  for (int mt = 0; mt < 4; ++mt)
#pragma unroll
    for (int nt = 0; nt < 2; ++nt) acc[mt][nt] = f32x4{0.f, 0.f, 0.f, 0.f};

  s16x8 sa[3][4], sb[3][2];   // 3 rotating slots, depth-2 prefetch
  gload(Af, Bf, Mt0, Nt0, 0, lane, sa[0], sb[0]);
  gload(Af, Bf, Mt0, Nt0, 1, lane, sa[1], sb[1]);
#pragma unroll
  for (int kt = 0; kt < 8; ++kt) {
    if (kt + 2 < 8)
      gload(Af, Bf, Mt0, Nt0, kt + 2, lane, sa[(kt + 2) % 3], sb[(kt + 2) % 3]);
    gmfma(sa[kt % 3], sb[kt % 3], acc, swap);
  }

  if (PROJ) {
#pragma unroll
    for (int mt = 0; mt < 4; ++mt) {
      const int mbase = m0 + mt * 16 + 4 * grp;
      const float4 bv = *(const float4*)(bias + mbase);
      const float bvr[4] = {bv.x, bv.y, bv.z, bv.w};
#pragma unroll
      for (int nt = 0; nt < 2; ++nt) {
        const int pos = n0 + nt * 16 + li;
#pragma unroll
        for (int r = 0; r < 4; ++r) {
          const size_t ob = ((size_t)(b * 256 + mbase + r)) * 1024 + pos;
          outp[ob] = acc[mt][nt][r] + bvr[r] + res[ob];
        }
      }
    }
  } else if (!swap) {
    // Q/K: D rows = ch (4grp+r), cols = pos (li). Q gets kQScale folded in.
    unsigned short* __restrict__ Tp = (mb < 2) ? Qp : Kp;
    const float qs = (mb < 2) ? kQScale : 1.0f;
#pragma unroll
    for (int mt = 0; mt < 4; ++mt) {
      const int mbase = m0 + mt * 16;
      const int head = (mbase >> 6) & 3;
      const int bh = b * 4 + head;
      const int c16 = mbase & 63;
      const int ks = c16 >> 5;
      const int grpp = ((c16 >> 3) + (grp >> 1)) & 3;
      const float4 bv = *(const float4*)(bias + mbase + 4 * grp);
#pragma unroll
      for (int nt = 0; nt < 2; ++nt) {
        const int pt = (n0 >> 4) + nt;
        ushort4 o;
        o.x = f2bf((acc[mt][nt][0] + bv.x) * qs);
        o.y = f2bf((acc[mt][nt][1] + bv.y) * qs);
        o.z = f2bf((acc[mt][nt][2] + bv.z) * qs);
        o.w = f2bf((acc[mt][nt][3] + bv.w) * qs);
        *(ushort4*)(Tp + (size_t)bh * 65536 +
                    ((size_t)(pt * 2 + ks) * 64 + grpp * 16 + li) * 8 +
                    (grp & 1) * 4) = o;
      }
    }
  } else {
    // V: D rows = pos (4grp+r), cols = ch (li).
#pragma unroll
    for (int mt = 0; mt < 4; ++mt) {
      const int mbase = m0 + mt * 16;
      const int head = (mbase >> 6) & 3;
      const int bh = b * 4 + head;
      const int ct = (mbase & 63) >> 4;
      const float bvc = bias[mbase + li];
      const int kvt = n0 >> 5;
#pragma unroll
      for (int nt = 0; nt < 2; ++nt) {
        const int grpv = (nt * 2 + (grp >> 1)) & 3;
        ushort4 o;
        o.x = f2bf(acc[mt][nt][0] + bvc);
        o.y = f2bf(acc[mt][nt][1] + bvc);
        o.z = f2bf(acc[mt][nt][2] + bvc);
        o.w = f2bf(acc[mt][nt][3] + bvc);
        *(ushort4*)(Vp + (size_t)bh * 65536 +
                    ((size_t)(ct * 32 + kvt) * 64 + grpv * 16 + li) * 8 +
                    (grp & 1) * 4) = o;
      }
    }
  }
}

// ---------------------------------------------------------------------------
// MFMA flash attention, software-pipelined one KV-tile deep:
//  S(t+1) MFMA + K(t+2)/V(t+1) load issue happen BEFORE softmax+PV of tile t,
//  so matrix-pipe latency hides under the previous tile's VALU softmax.
// ---------------------------------------------------------------------------
__global__ __launch_bounds__(256) void attn_mfma_kernel(
    const unsigned short* __restrict__ Qp, const unsigned short* __restrict__ Kp,
    const unsigned short* __restrict__ Vp, unsigned short* __restrict__ aoTp) {
  __shared__ unsigned short P_lds[4][16][56];
  const int bid = blockIdx.x;
  const int swz = (bid & 7) * 64 + (bid >> 3);   // 512 = 8 * 64, bijective
  const int bh = swz >> 4, qb = swz & 15;
  const int b = bh >> 2, head = bh & 3;
  const int t = threadIdx.x;
  const int wave = t >> 6, lane = t & 63;
  const int li = lane & 15, grp = lane >> 4;
  const int q0 = qb * 64 + wave * 16;
  const unsigned short* __restrict__ Qb = Qp + (size_t)bh * 65536;
  const unsigned short* __restrict__ Kb = Kp + (size_t)bh * 65536;
  const unsigned short* __restrict__ Vb = Vp + (size_t)bh * 65536;

  s16x8 qf[2];
#pragma unroll
  for (int ks = 0; ks < 2; ++ks)
    qf[ks] = *(const s16x8*)(Qb + (((q0 >> 4) * 2 + ks) * 64 + lane) * 8);

  f32x4 O[4];
#pragma unroll
  for (int ct = 0; ct < 4; ++ct) O[ct] = f32x4{0.f, 0.f, 0.f, 0.f};
  f32x4 lvec = f32x4{0.f, 0.f, 0.f, 0.f};
  float m_run = -1.0e30f;

  auto loadK = [&](int it, s16x8 (&kk)[2][2]) {
#pragma unroll
    for (int mt = 0; mt < 2; ++mt)
#pragma unroll
      for (int ks = 0; ks < 2; ++ks)
        kk[mt][ks] = *(const s16x8*)(
            Kb + ((size_t)((it * 2 + mt) * 2 + ks) * 64 + lane) * 8);
  };
  auto loadV = [&](int it, s16x8 (&vv)[4]) {
#pragma unroll
    for (int ct = 0; ct < 4; ++ct)
      vv[ct] = *(const s16x8*)(Vb + ((size_t)(ct * 32 + it) * 64 + lane) * 8);
  };
  auto qkt = [&](const s16x8 (&kk)[2][2], f32x4 (&s)[2]) {
#pragma unroll
    for (int mt = 0; mt < 2; ++mt) {
      s[mt] = mfma16(kk[mt][0], qf[0], f32x4{0.f, 0.f, 0.f, 0.f});
      s[mt] = mfma16(kk[mt][1], qf[1], s[mt]);
    }
  };
  // softmax(s) + P-pack + PV-accumulate with V frags vv
  auto smaxpv = [&](f32x4 (&s)[2], const s16x8 (&vv)[4]) {
    const float A = fmaxf(fmaxf(s[0][0], s[0][1]), s[0][2]);
    const float B = fmaxf(fmaxf(s[0][3], s[1][0]), s[1][1]);
    const float C = fmaxf(fmaxf(s[1][2], s[1][3]), A);
    float pm = fmaxf(B, C);
    pm = fmaxf(pm, __shfl_xor(pm, 16));
    pm = fmaxf(pm, __shfl_xor(pm, 32));
    if (!__all(pm <= m_run + 8.0f)) {   // defer-max rescale (exp2 units)
      const float mnew = fmaxf(m_run, pm);
      const float f = exp2_fast(m_run - mnew);
      m_run = mnew;
      lvec *= f;
#pragma unroll
      for (int ct = 0; ct < 4; ++ct) O[ct] *= f;
    }
    f32x4 p[2];
#pragma unroll
    for (int mt = 0; mt < 2; ++mt) {
#pragma unroll
      for (int r = 0; r < 4; ++r) p[mt][r] = exp2_fast(s[mt][r] - m_run);
      lvec += p[mt];
    }
#pragma unroll
    for (int mt = 0; mt < 2; ++mt) {
      uint2 cc;
      cc.x = cvt_pk_bf16(p[mt][0], p[mt][1]);
      cc.y = cvt_pk_bf16(p[mt][2], p[mt][3]);
      *(uint2*)&P_lds[wave][li][16 * mt + 4 * grp] = cc;
    }
    const s16x8 pf = *(const s16x8*)&P_lds[wave][li][8 * grp];
#pragma unroll
    for (int ct = 0; ct < 4; ++ct) O[ct] = mfma16(vv[ct], pf, O[ct]);
  };

  s16x8 k0[2][2], k1[2][2], v0[4], v1[4];
  loadK(0, k0);
  loadV(0, v0);
  f32x4 sc[2];
  qkt(k0, sc);        // S(0)
  loadK(1, k1);

  // Tail iterations overread K(33)/V(32) into adjacent ws regions (allocated;
  // values computed but never used) — keeps the loop branchless.
#pragma unroll 1
  for (int h2 = 0; h2 < 16; ++h2) {
    const int tt = 2 * h2;
    // half A: pipeline tile tt+1, finish tile tt
    loadV(tt + 1, v1);
    f32x4 sn[2];
    qkt(k1, sn);            // S(tt+1)
    loadK(tt + 2, k0);
    smaxpv(sc, v0);         // softmax+PV of tile tt
    // half B: pipeline tile tt+2, finish tile tt+1
    loadV(tt + 2, v0);
    f32x4 s2[2];
    qkt(k0, s2);            // S(tt+2)
    loadK(tt + 3, k1);
    smaxpv(sn, v1);         // softmax+PV of tile tt+1
    sc[0] = s2[0];
    sc[1] = s2[1];
  }

  float lt = lvec[0] + lvec[1] + lvec[2] + lvec[3];
  lt += __shfl_xor(lt, 16);
  lt += __shfl_xor(lt, 32);
  const float rinv = 1.f / lt;
  // write aoTp packed frags: q = q0+li, c = head*64 + ct*16 + 4*grp + r
#pragma unroll
  for (int ct = 0; ct < 4; ++ct) {
    const int ktp = head * 2 + (ct >> 1);
    const int grpp = ((ct & 1) * 2 + (grp >> 1)) & 3;
    ushort4 o;
    o.x = f2bf(O[ct][0] * rinv);
    o.y = f2bf(O[ct][1] * rinv);
    o.z = f2bf(O[ct][2] * rinv);
    o.w = f2bf(O[ct][3] * rinv);
    *(ushort4*)(aoTp +
                ((size_t)((b * 64 + (q0 >> 4)) * 8 + ktp) * 64 + grpp * 16 + li) * 8 +
                (grp & 1) * 4) = o;
  }
}

// ---------------------------------------------------------------------------
extern "C" void kernel_launch(void* const* d_in, const int* in_sizes, int n_in,
                              void* d_out, int out_size, void* d_ws, size_t ws_size,
                              hipStream_t stream) {
  const float* x      = (const float*)d_in[0];
  const float* gamma  = (const float*)d_in[1];
  const float* beta   = (const float*)d_in[2];
  const float* w_qkv  = (const float*)d_in[3];
  const float* b_qkv  = (const float*)d_in[4];
  const float* w_proj = (const float*)d_in[5];
  const float* b_proj = (const float*)d_in[6];
  float* out = (float*)d_out;

  unsigned short* ws = (unsigned short*)d_ws;
  unsigned short* Wqp  = ws;                    // 196608
  unsigned short* Wpp  = Wqp + 196608;          // 65536
  unsigned short* hTp  = Wpp + 65536;           // 2097152
  unsigned short* Qp   = hTp + 2097152;         // 2097152
  unsigned short* Kp   = Qp + 2097152;          // 2097152
  unsigned short* Vp   = Kp + 2097152;          // 2097152
  unsigned short* aoTp = Vp + 2097152;          // 2097152 (+ slack for overreads)

  hipLaunchKernelGGL(prep_kernel, dim3(384), dim3(256), 0, stream,
                     x, gamma, beta, hTp, w_qkv, w_proj, Wqp, Wpp);
  hipLaunchKernelGGL((gemm_pk_kernel<6, false>), dim3(768), dim3(256), 0, stream,
                     Wqp, b_qkv, hTp, Qp, Kp, Vp, nullptr, nullptr);
  hipLaunchKernelGGL(attn_mfma_kernel, dim3(512), dim3(256), 0, stream,
                     Qp, Kp, Vp, aoTp);
  hipLaunchKernelGGL((gemm_pk_kernel<2, true>), dim3(256), dim3(256), 0, stream,
                     Wpp, b_proj, aoTp, nullptr, nullptr, nullptr, x, out);
}

// Round 8
// 42.306 us; speedup vs baseline: 3.0104x; 1.0179x over previous
//
#include <hip/hip_runtime.h>
#include <hip/hip_bf16.h>

static constexpr int kC = 256;
static constexpr int kN = 1024;   // H*W

using s16x8 = __attribute__((ext_vector_type(8))) short;
using f32x4 = __attribute__((ext_vector_type(4))) float;

__device__ inline f32x4 mfma16(s16x8 a, s16x8 b, f32x4 c) {
  return __builtin_amdgcn_mfma_f32_16x16x32_bf16(a, b, c, 0, 0, 0);
}

__device__ inline unsigned short f2bf(float f) {   // RNE
  unsigned u = __builtin_bit_cast(unsigned, f);
  u = (u + 0x7fffu + ((u >> 16) & 1u)) >> 16;
  return (unsigned short)u;
}

__device__ inline float exp2_fast(float x) {   // 2^x, single v_exp_f32
  float r;
  asm("v_exp_f32 %0, %1" : "=v"(r) : "v"(x));
  return r;
}

__device__ inline unsigned cvt_pk_bf16(float lo, float hi) {
  unsigned r;
  asm("v_cvt_pk_bf16_f32 %0, %1, %2" : "=v"(r) : "v"(lo), "v"(hi));
  return r;
}

// 1/sqrt(64) * log2(e): folded into Q so QK^T lands in exp2 units.
static constexpr float kQScale = 0.18033688011112042f;

// ---------------------------------------------------------------------------
// prep: blocks 0..127 pack weights into A-frag layout; blocks 128..383 GN.
// ---------------------------------------------------------------------------
__global__ __launch_bounds__(256) void prep_kernel(
    const float* __restrict__ x, const float* __restrict__ gamma,
    const float* __restrict__ beta, unsigned short* __restrict__ hTp,
    const float* __restrict__ wq, const float* __restrict__ wp,
    unsigned short* __restrict__ Wqp, unsigned short* __restrict__ Wpp) {
  if (blockIdx.x < 128) {
    const int tid = blockIdx.x * 256 + threadIdx.x;   // 0..32767
    const float* src;
    unsigned short* dst;
    if (tid < 24576) {
      const int fragid = tid >> 6, lane = tid & 63;
      const int Mt = fragid >> 3, kt = fragid & 7;
      src = wq + (size_t)(Mt * 16 + (lane & 15)) * 256 + kt * 32 + (lane >> 4) * 8;
      dst = Wqp + (size_t)tid * 8;
    } else {
      const int id = tid - 24576;
      const int fragid = id >> 6, lane = id & 63;
      const int Mt = fragid >> 3, kt = fragid & 7;
      src = wp + (size_t)(Mt * 16 + (lane & 15)) * 256 + kt * 32 + (lane >> 4) * 8;
      dst = Wpp + (size_t)id * 8;
    }
    const float4 f0 = *(const float4*)src;
    const float4 f1 = *(const float4*)(src + 4);
    ushort4 o0, o1;
    o0.x = f2bf(f0.x); o0.y = f2bf(f0.y); o0.z = f2bf(f0.z); o0.w = f2bf(f0.w);
    o1.x = f2bf(f1.x); o1.y = f2bf(f1.y); o1.z = f2bf(f1.z); o1.w = f2bf(f1.w);
    *(ushort4*)dst = o0;
    *(ushort4*)(dst + 4) = o1;
    return;
  }

  const int bg = blockIdx.x - 128;
  const int b = bg >> 5, g = bg & 31;
  const size_t base = ((size_t)b * kC + (size_t)g * 8) * kN;
  const float4* __restrict__ x4 = (const float4*)(x + base);
  const int t = threadIdx.x;

  float vv[8][4];
  float s = 0.f, ss = 0.f;
#pragma unroll
  for (int i = 0; i < 8; ++i) {
    const float4 v = x4[t + 256 * i];
    vv[i][0] = v.x; vv[i][1] = v.y; vv[i][2] = v.z; vv[i][3] = v.w;
    s += v.x + v.y + v.z + v.w;
    ss += v.x * v.x + v.y * v.y + v.z * v.z + v.w * v.w;
  }
#pragma unroll
  for (int off = 32; off > 0; off >>= 1) {
    s += __shfl_xor(s, off);
    ss += __shfl_xor(ss, off);
  }
  __shared__ float rs[4], rss[4];
  const int wave = t >> 6, lane = t & 63;
  if (lane == 0) { rs[wave] = s; rss[wave] = ss; }
  __syncthreads();
  s = rs[0] + rs[1] + rs[2] + rs[3];
  ss = rss[0] + rss[1] + rss[2] + rss[3];
  const float mean = s * (1.f / 8192.f);
  const float var = ss * (1.f / 8192.f) - mean * mean;
  const float rinv = rsqrtf(var + 1e-5f);
  float ga[8], be[8];
#pragma unroll
  for (int i = 0; i < 8; ++i) {
    ga[i] = gamma[g * 8 + i] * rinv;
    be[i] = beta[g * 8 + i] - mean * ga[i];
  }
  const int kt = g >> 2, gq = g & 3;
#pragma unroll
  for (int r = 0; r < 4; ++r) {
    const int pos = 4 * t + r;
    const int nt = pos >> 4, lp = pos & 15;
    unsigned short* dst =
        hTp + ((size_t)((b * 64 + nt) * 8 + kt) * 64 + (gq * 16 + lp)) * 8;
    ushort4 o0, o1;
    o0.x = f2bf(vv[0][r] * ga[0] + be[0]);
    o0.y = f2bf(vv[1][r] * ga[1] + be[1]);
    o0.z = f2bf(vv[2][r] * ga[2] + be[2]);
    o0.w = f2bf(vv[3][r] * ga[3] + be[3]);
    o1.x = f2bf(vv[4][r] * ga[4] + be[4]);
    o1.y = f2bf(vv[5][r] * ga[5] + be[5]);
    o1.z = f2bf(vv[6][r] * ga[6] + be[6]);
    o1.w = f2bf(vv[7][r] * ga[7] + be[7]);
    *(ushort4*)dst = o0;
    *(ushort4*)(dst + 4) = o1;
  }
}

// ---------------------------------------------------------------------------
// LDS-free bf16 MFMA QKV GEMM, depth-2 register prefetch (3 rotating slots).
// Block: 4 waves (2m x 2n), tile 128m x 64n; wave 64m x 32n; K=256.
// ---------------------------------------------------------------------------
__device__ inline void gload(const s16x8* __restrict__ Af,
                             const s16x8* __restrict__ Bf,
                             int Mt0, int Nt0, int kt, int lane,
                             s16x8 (&a)[4], s16x8 (&bb)[2]) {
#pragma unroll
  for (int mt = 0; mt < 4; ++mt)
    a[mt] = Af[((size_t)(Mt0 + mt) * 8 + kt) * 64 + lane];
#pragma unroll
  for (int nt = 0; nt < 2; ++nt)
    bb[nt] = Bf[((size_t)(Nt0 + nt) * 8 + kt) * 64 + lane];
}

__device__ inline void gmfma(const s16x8 (&a)[4], const s16x8 (&bb)[2],
                             f32x4 (&acc)[4][2], bool swap) {
  if (swap) {
#pragma unroll
    for (int mt = 0; mt < 4; ++mt)
#pragma unroll
      for (int nt = 0; nt < 2; ++nt)
        acc[mt][nt] = mfma16(bb[nt], a[mt], acc[mt][nt]);
  } else {
#pragma unroll
    for (int mt = 0; mt < 4; ++mt)
#pragma unroll
      for (int nt = 0; nt < 2; ++nt)
        acc[mt][nt] = mfma16(a[mt], bb[nt], acc[mt][nt]);
  }
}

__global__ __launch_bounds__(256) void gemm_qkv_kernel(
    const unsigned short* __restrict__ Wp, const float* __restrict__ bias,
    const unsigned short* __restrict__ Bp,
    unsigned short* __restrict__ Qp, unsigned short* __restrict__ Kp,
    unsigned short* __restrict__ Vp) {
  const int bid = blockIdx.x;
  const int swz = (bid & 7) * 96 + (bid >> 3);
  const int b = swz / 96, rr = swz % 96;
  const int mb = rr >> 4, nb = rr & 15;
  const int t = threadIdx.x;
  const int wave = t >> 6, lane = t & 63;
  const int li = lane & 15, grp = lane >> 4;
  const int m0 = mb * 128 + (wave >> 1) * 64;
  const int n0 = nb * 64 + (wave & 1) * 32;
  const bool swap = mb >= 4;   // V tiles
  const int Mt0 = m0 >> 4;
  const int Nt0 = b * 64 + (n0 >> 4);
  const s16x8* __restrict__ Af = (const s16x8*)Wp;
  const s16x8* __restrict__ Bf = (const s16x8*)Bp;

  f32x4 acc[4][2];
#pragma unroll
  for (int mt = 0; mt < 4; ++mt)
#pragma unroll
    for (int nt = 0; nt < 2; ++nt) acc[mt][nt] = f32x4{0.f, 0.f, 0.f, 0.f};

  s16x8 sa[3][4], sb[3][2];   // 3 rotating slots, depth-2 prefetch
  gload(Af, Bf, Mt0, Nt0, 0, lane, sa[0], sb[0]);
  gload(Af, Bf, Mt0, Nt0, 1, lane, sa[1], sb[1]);
#pragma unroll
  for (int kt = 0; kt < 8; ++kt) {
    if (kt + 2 < 8)
      gload(Af, Bf, Mt0, Nt0, kt + 2, lane, sa[(kt + 2) % 3], sb[(kt + 2) % 3]);
    gmfma(sa[kt % 3], sb[kt % 3], acc, swap);
  }

  if (!swap) {
    // Q/K: D rows = ch (4grp+r), cols = pos (li). Q gets kQScale folded in.
    unsigned short* __restrict__ Tp = (mb < 2) ? Qp : Kp;
    const float qs = (mb < 2) ? kQScale : 1.0f;
#pragma unroll
    for (int mt = 0; mt < 4; ++mt) {
      const int mbase = m0 + mt * 16;
      const int head = (mbase >> 6) & 3;
      const int bh = b * 4 + head;
      const int c16 = mbase & 63;
      const int ks = c16 >> 5;
      const int grpp = ((c16 >> 3) + (grp >> 1)) & 3;
      const float4 bv = *(const float4*)(bias + mbase + 4 * grp);
#pragma unroll
      for (int nt = 0; nt < 2; ++nt) {
        const int pt = (n0 >> 4) + nt;
        ushort4 o;
        o.x = f2bf((acc[mt][nt][0] + bv.x) * qs);
        o.y = f2bf((acc[mt][nt][1] + bv.y) * qs);
        o.z = f2bf((acc[mt][nt][2] + bv.z) * qs);
        o.w = f2bf((acc[mt][nt][3] + bv.w) * qs);
        *(ushort4*)(Tp + (size_t)bh * 65536 +
                    ((size_t)(pt * 2 + ks) * 64 + grpp * 16 + li) * 8 +
                    (grp & 1) * 4) = o;
      }
    }
  } else {
    // V: D rows = pos (4grp+r), cols = ch (li).
#pragma unroll
    for (int mt = 0; mt < 4; ++mt) {
      const int mbase = m0 + mt * 16;
      const int head = (mbase >> 6) & 3;
      const int bh = b * 4 + head;
      const int ct = (mbase & 63) >> 4;
      const float bvc = bias[mbase + li];
      const int kvt = n0 >> 5;
#pragma unroll
      for (int nt = 0; nt < 2; ++nt) {
        const int grpv = (nt * 2 + (grp >> 1)) & 3;
        ushort4 o;
        o.x = f2bf(acc[mt][nt][0] + bvc);
        o.y = f2bf(acc[mt][nt][1] + bvc);
        o.z = f2bf(acc[mt][nt][2] + bvc);
        o.w = f2bf(acc[mt][nt][3] + bvc);
        *(ushort4*)(Vp + (size_t)bh * 65536 +
                    ((size_t)(ct * 32 + kvt) * 64 + grpv * 16 + li) * 8 +
                    (grp & 1) * 4) = o;
      }
    }
  }
}

// ---------------------------------------------------------------------------
// Fused flash-attention + proj. 256 blocks x 512 threads.
// Block = (b, 32 positions); 8 waves = 4 heads x 2 q-halves, each wave runs
// the pipelined 16-q attention loop, writes O into LDS shaped as proj
// B-frags, barrier, then each wave computes a 32(out-ch) x 32(pos) proj tile
// with fp32 + bias + residual epilogue.
// ---------------------------------------------------------------------------
__global__ __launch_bounds__(512) void attn_proj_kernel(
    const unsigned short* __restrict__ Qp, const unsigned short* __restrict__ Kp,
    const unsigned short* __restrict__ Vp, const unsigned short* __restrict__ Wpp,
    const float* __restrict__ bpj, const float* __restrict__ x,
    float* __restrict__ out) {
  __shared__ unsigned short P_lds[8][16][56];
  __shared__ __align__(16) unsigned short Ex[2][8][64][8];   // proj B-frags, 16 KB
  const int bid = blockIdx.x;
  const int swz = (bid & 7) * 32 + (bid >> 3);   // 256 = 8*32, bijective
  const int b = swz >> 5, qb = swz & 31;         // batch = XCD; qb: 32-pos block
  const int t = threadIdx.x;
  const int w8 = t >> 6, lane = t & 63;
  const int head = w8 & 3, qh = w8 >> 2;
  const int li = lane & 15, grp = lane >> 4;
  const int q0 = qb * 32 + qh * 16;
  const int bh = b * 4 + head;
  const unsigned short* __restrict__ Qb = Qp + (size_t)bh * 65536;
  const unsigned short* __restrict__ Kb = Kp + (size_t)bh * 65536;
  const unsigned short* __restrict__ Vb = Vp + (size_t)bh * 65536;

  s16x8 qf[2];
#pragma unroll
  for (int ks = 0; ks < 2; ++ks)
    qf[ks] = *(const s16x8*)(Qb + (((q0 >> 4) * 2 + ks) * 64 + lane) * 8);

  f32x4 O[4];
#pragma unroll
  for (int ct = 0; ct < 4; ++ct) O[ct] = f32x4{0.f, 0.f, 0.f, 0.f};
  f32x4 lvec = f32x4{0.f, 0.f, 0.f, 0.f};
  float m_run = -1.0e30f;

  auto loadK = [&](int it, s16x8 (&kk)[2][2]) {
#pragma unroll
    for (int mt = 0; mt < 2; ++mt)
#pragma unroll
      for (int ks = 0; ks < 2; ++ks)
        kk[mt][ks] = *(const s16x8*)(
            Kb + ((size_t)((it * 2 + mt) * 2 + ks) * 64 + lane) * 8);
  };
  auto loadV = [&](int it, s16x8 (&vv)[4]) {
#pragma unroll
    for (int ct = 0; ct < 4; ++ct)
      vv[ct] = *(const s16x8*)(Vb + ((size_t)(ct * 32 + it) * 64 + lane) * 8);
  };
  auto qkt = [&](const s16x8 (&kk)[2][2], f32x4 (&s)[2]) {
#pragma unroll
    for (int mt = 0; mt < 2; ++mt) {
      s[mt] = mfma16(kk[mt][0], qf[0], f32x4{0.f, 0.f, 0.f, 0.f});
      s[mt] = mfma16(kk[mt][1], qf[1], s[mt]);
    }
  };
  auto smaxpv = [&](f32x4 (&s)[2], const s16x8 (&vv)[4]) {
    const float A = fmaxf(fmaxf(s[0][0], s[0][1]), s[0][2]);
    const float B = fmaxf(fmaxf(s[0][3], s[1][0]), s[1][1]);
    const float C = fmaxf(fmaxf(s[1][2], s[1][3]), A);
    float pm = fmaxf(B, C);
    pm = fmaxf(pm, __shfl_xor(pm, 16));
    pm = fmaxf(pm, __shfl_xor(pm, 32));
    if (!__all(pm <= m_run + 8.0f)) {   // defer-max rescale (exp2 units)
      const float mnew = fmaxf(m_run, pm);
      const float f = exp2_fast(m_run - mnew);
      m_run = mnew;
      lvec *= f;
#pragma unroll
      for (int ct = 0; ct < 4; ++ct) O[ct] *= f;
    }
    f32x4 p[2];
#pragma unroll
    for (int mt = 0; mt < 2; ++mt) {
#pragma unroll
      for (int r = 0; r < 4; ++r) p[mt][r] = exp2_fast(s[mt][r] - m_run);
      lvec += p[mt];
    }
#pragma unroll
    for (int mt = 0; mt < 2; ++mt) {
      uint2 cc;
      cc.x = cvt_pk_bf16(p[mt][0], p[mt][1]);
      cc.y = cvt_pk_bf16(p[mt][2], p[mt][3]);
      *(uint2*)&P_lds[w8][li][16 * mt + 4 * grp] = cc;
    }
    const s16x8 pf = *(const s16x8*)&P_lds[w8][li][8 * grp];
#pragma unroll
    for (int ct = 0; ct < 4; ++ct) O[ct] = mfma16(vv[ct], pf, O[ct]);
  };

  s16x8 k0[2][2], k1[2][2], v0[4], v1[4];
  loadK(0, k0);
  loadV(0, v0);
  f32x4 sc[2];
  qkt(k0, sc);        // S(0)
  loadK(1, k1);

  // Tail iterations overread K(33)/V(32) into adjacent ws regions (allocated;
  // values computed but never used) — keeps the loop branchless.
#pragma unroll 1
  for (int h2 = 0; h2 < 16; ++h2) {
    const int tt = 2 * h2;
    loadV(tt + 1, v1);
    f32x4 sn[2];
    qkt(k1, sn);            // S(tt+1)
    loadK(tt + 2, k0);
    smaxpv(sc, v0);         // finish tile tt
    loadV(tt + 2, v0);
    f32x4 s2[2];
    qkt(k0, s2);            // S(tt+2)
    loadK(tt + 3, k1);
    smaxpv(sn, v1);         // finish tile tt+1
    sc[0] = s2[0];
    sc[1] = s2[1];
  }

  float lt = lvec[0] + lvec[1] + lvec[2] + lvec[3];
  lt += __shfl_xor(lt, 16);
  lt += __shfl_xor(lt, 32);
  const float rinv = 1.f / lt;
  // O -> LDS proj-B-frags: q = q0+li (local pos-tile qh), c = head*64+ct*16+4grp+r
#pragma unroll
  for (int ct = 0; ct < 4; ++ct) {
    const int ktp = head * 2 + (ct >> 1);
    const int grpp = ((ct & 1) * 2 + (grp >> 1)) & 3;
    ushort4 o;
    o.x = f2bf(O[ct][0] * rinv);
    o.y = f2bf(O[ct][1] * rinv);
    o.z = f2bf(O[ct][2] * rinv);
    o.w = f2bf(O[ct][3] * rinv);
    *(ushort4*)&Ex[qh][ktp][grpp * 16 + li][(grp & 1) * 4] = o;
  }
  __syncthreads();

  // ---- proj: wave w8 computes out rows m0 = w8*32 .. +31, 32 positions ----
  {
    const int Mt0 = w8 * 2;
    const s16x8* __restrict__ Af = (const s16x8*)Wpp;
    f32x4 acc[2][2];
#pragma unroll
    for (int mt = 0; mt < 2; ++mt)
#pragma unroll
      for (int nt = 0; nt < 2; ++nt) acc[mt][nt] = f32x4{0.f, 0.f, 0.f, 0.f};

    s16x8 pa[3][2];
    auto loadA = [&](int kt, s16x8 (&a)[2]) {
#pragma unroll
      for (int mt = 0; mt < 2; ++mt)
        a[mt] = Af[((size_t)(Mt0 + mt) * 8 + kt) * 64 + lane];
    };
    loadA(0, pa[0]);
    loadA(1, pa[1]);
#pragma unroll
    for (int kt = 0; kt < 8; ++kt) {
      if (kt + 2 < 8) loadA(kt + 2, pa[(kt + 2) % 3]);
      s16x8 bb[2];
#pragma unroll
      for (int nt = 0; nt < 2; ++nt)
        bb[nt] = *(const s16x8*)&Ex[nt][kt][lane][0];
#pragma unroll
      for (int mt = 0; mt < 2; ++mt)
#pragma unroll
        for (int nt = 0; nt < 2; ++nt)
          acc[mt][nt] = mfma16(pa[kt % 3][mt], bb[nt], acc[mt][nt]);
    }

#pragma unroll
    for (int mt = 0; mt < 2; ++mt) {
      const int mbase = w8 * 32 + mt * 16 + 4 * grp;
      const float4 bv = *(const float4*)(bpj + mbase);
      const float bvr[4] = {bv.x, bv.y, bv.z, bv.w};
#pragma unroll
      for (int nt = 0; nt < 2; ++nt) {
        const int pos = qb * 32 + nt * 16 + li;
#pragma unroll
        for (int r2 = 0; r2 < 4; ++r2) {
          const size_t ob = ((size_t)(b * 256 + mbase + r2)) * 1024 + pos;
          out[ob] = acc[mt][nt][r2] + bvr[r2] + x[ob];
        }
      }
    }
  }
}

// ---------------------------------------------------------------------------
extern "C" void kernel_launch(void* const* d_in, const int* in_sizes, int n_in,
                              void* d_out, int out_size, void* d_ws, size_t ws_size,
                              hipStream_t stream) {
  const float* x      = (const float*)d_in[0];
  const float* gamma  = (const float*)d_in[1];
  const float* beta   = (const float*)d_in[2];
  const float* w_qkv  = (const float*)d_in[3];
  const float* b_qkv  = (const float*)d_in[4];
  const float* w_proj = (const float*)d_in[5];
  const float* b_proj = (const float*)d_in[6];
  float* out = (float*)d_out;

  unsigned short* ws = (unsigned short*)d_ws;
  unsigned short* Wqp  = ws;                    // 196608
  unsigned short* Wpp  = Wqp + 196608;          // 65536
  unsigned short* hTp  = Wpp + 65536;           // 2097152
  unsigned short* Qp   = hTp + 2097152;         // 2097152
  unsigned short* Kp   = Qp + 2097152;          // 2097152
  unsigned short* Vp   = Kp + 2097152;          // 2097152 (+2MB slack for overreads)

  hipLaunchKernelGGL(prep_kernel, dim3(384), dim3(256), 0, stream,
                     x, gamma, beta, hTp, w_qkv, w_proj, Wqp, Wpp);
  hipLaunchKernelGGL(gemm_qkv_kernel, dim3(768), dim3(256), 0, stream,
                     Wqp, b_qkv, hTp, Qp, Kp, Vp);
  hipLaunchKernelGGL(attn_proj_kernel, dim3(256), dim3(512), 0, stream,
                     Qp, Kp, Vp, Wpp, b_proj, x, out);
}

// Round 9
// 41.695 us; speedup vs baseline: 3.0546x; 1.0147x over previous
//
#include <hip/hip_runtime.h>
#include <hip/hip_bf16.h>

static constexpr int kC = 256;
static constexpr int kN = 1024;   // H*W

using s16x8 = __attribute__((ext_vector_type(8))) short;
using f32x4 = __attribute__((ext_vector_type(4))) float;
using u32x4 = __attribute__((ext_vector_type(4))) unsigned int;

__device__ inline f32x4 mfma16(s16x8 a, s16x8 b, f32x4 c) {
  return __builtin_amdgcn_mfma_f32_16x16x32_bf16(a, b, c, 0, 0, 0);
}

__device__ inline unsigned short f2bf(float f) {   // RNE
  unsigned u = __builtin_bit_cast(unsigned, f);
  u = (u + 0x7fffu + ((u >> 16) & 1u)) >> 16;
  return (unsigned short)u;
}

__device__ inline float exp2_fast(float x) {   // 2^x, single v_exp_f32
  float r;
  asm("v_exp_f32 %0, %1" : "=v"(r) : "v"(x));
  return r;
}

__device__ inline unsigned cvt_pk_bf16(float lo, float hi) {
  unsigned r;
  asm("v_cvt_pk_bf16_f32 %0, %1, %2" : "=v"(r) : "v"(lo), "v"(hi));
  return r;
}

// 1/sqrt(64) * log2(e): folded into Q so QK^T lands in exp2 units.
static constexpr float kQScale = 0.18033688011112042f;

// ---------------------------------------------------------------------------
// prep: blocks 0..127 pack weights into A-frag layout; blocks 128..383 GN.
// GN batch = XCD (b = bg&7) so hTp is produced on the L2 that consumes it.
// ---------------------------------------------------------------------------
__global__ __launch_bounds__(256) void prep_kernel(
    const float* __restrict__ x, const float* __restrict__ gamma,
    const float* __restrict__ beta, unsigned short* __restrict__ hTp,
    const float* __restrict__ wq, const float* __restrict__ wp,
    unsigned short* __restrict__ Wqp, unsigned short* __restrict__ Wpp) {
  if (blockIdx.x < 128) {
    const int tid = blockIdx.x * 256 + threadIdx.x;   // 0..32767
    const float* src;
    unsigned short* dst;
    if (tid < 24576) {
      const int fragid = tid >> 6, lane = tid & 63;
      const int Mt = fragid >> 3, kt = fragid & 7;
      src = wq + (size_t)(Mt * 16 + (lane & 15)) * 256 + kt * 32 + (lane >> 4) * 8;
      dst = Wqp + (size_t)tid * 8;
    } else {
      const int id = tid - 24576;
      const int fragid = id >> 6, lane = id & 63;
      const int Mt = fragid >> 3, kt = fragid & 7;
      src = wp + (size_t)(Mt * 16 + (lane & 15)) * 256 + kt * 32 + (lane >> 4) * 8;
      dst = Wpp + (size_t)id * 8;
    }
    const float4 f0 = *(const float4*)src;
    const float4 f1 = *(const float4*)(src + 4);
    ushort4 o0, o1;
    o0.x = f2bf(f0.x); o0.y = f2bf(f0.y); o0.z = f2bf(f0.z); o0.w = f2bf(f0.w);
    o1.x = f2bf(f1.x); o1.y = f2bf(f1.y); o1.z = f2bf(f1.z); o1.w = f2bf(f1.w);
    *(ushort4*)dst = o0;
    *(ushort4*)(dst + 4) = o1;
    return;
  }

  const int bg = blockIdx.x - 128;
  const int b = bg & 7, g = bg >> 3;   // batch = XCD
  const size_t base = ((size_t)b * kC + (size_t)g * 8) * kN;
  const float4* __restrict__ x4 = (const float4*)(x + base);
  const int t = threadIdx.x;

  float vv[8][4];
  float s = 0.f, ss = 0.f;
#pragma unroll
  for (int i = 0; i < 8; ++i) {
    const float4 v = x4[t + 256 * i];
    vv[i][0] = v.x; vv[i][1] = v.y; vv[i][2] = v.z; vv[i][3] = v.w;
    s += v.x + v.y + v.z + v.w;
    ss += v.x * v.x + v.y * v.y + v.z * v.z + v.w * v.w;
  }
#pragma unroll
  for (int off = 32; off > 0; off >>= 1) {
    s += __shfl_xor(s, off);
    ss += __shfl_xor(ss, off);
  }
  __shared__ float rs[4], rss[4];
  const int wave = t >> 6, lane = t & 63;
  if (lane == 0) { rs[wave] = s; rss[wave] = ss; }
  __syncthreads();
  s = rs[0] + rs[1] + rs[2] + rs[3];
  ss = rss[0] + rss[1] + rss[2] + rss[3];
  const float mean = s * (1.f / 8192.f);
  const float var = ss * (1.f / 8192.f) - mean * mean;
  const float rinv = rsqrtf(var + 1e-5f);
  float ga[8], be[8];
#pragma unroll
  for (int i = 0; i < 8; ++i) {
    ga[i] = gamma[g * 8 + i] * rinv;
    be[i] = beta[g * 8 + i] - mean * ga[i];
  }
  const int kt = g >> 2, gq = g & 3;
#pragma unroll
  for (int r = 0; r < 4; ++r) {
    const int pos = 4 * t + r;
    const int nt = pos >> 4, lp = pos & 15;
    unsigned short* dst =
        hTp + ((size_t)((b * 64 + nt) * 8 + kt) * 64 + (gq * 16 + lp)) * 8;
    ushort4 o0, o1;
    o0.x = f2bf(vv[0][r] * ga[0] + be[0]);
    o0.y = f2bf(vv[1][r] * ga[1] + be[1]);
    o0.z = f2bf(vv[2][r] * ga[2] + be[2]);
    o0.w = f2bf(vv[3][r] * ga[3] + be[3]);
    o1.x = f2bf(vv[4][r] * ga[4] + be[4]);
    o1.y = f2bf(vv[5][r] * ga[5] + be[5]);
    o1.z = f2bf(vv[6][r] * ga[6] + be[6]);
    o1.w = f2bf(vv[7][r] * ga[7] + be[7]);
    *(ushort4*)dst = o0;
    *(ushort4*)(dst + 4) = o1;
  }
}

// ---------------------------------------------------------------------------
// LDS-free bf16 MFMA QKV GEMM, depth-2 register prefetch (3 rotating slots).
// Block: 4 waves (2m x 2n), tile 128m x 64n; wave 64m x 32n; K=256.
// V is stored with sigma-permuted columns: j = 16*(s>>2) + 4g + (s&3) at
// lane-slot (g, s) -> write addr slot grp*16+li, ushort offset nt*4 (+r).
// This makes attention's post-softmax P registers directly usable as the
// PV B-frag (no LDS round trip).
// ---------------------------------------------------------------------------
__device__ inline void gload(const s16x8* __restrict__ Af,
                             const s16x8* __restrict__ Bf,
                             int Mt0, int Nt0, int kt, int lane,
                             s16x8 (&a)[4], s16x8 (&bb)[2]) {
#pragma unroll
  for (int mt = 0; mt < 4; ++mt)
    a[mt] = Af[((size_t)(Mt0 + mt) * 8 + kt) * 64 + lane];
#pragma unroll
  for (int nt = 0; nt < 2; ++nt)
    bb[nt] = Bf[((size_t)(Nt0 + nt) * 8 + kt) * 64 + lane];
}

__device__ inline void gmfma(const s16x8 (&a)[4], const s16x8 (&bb)[2],
                             f32x4 (&acc)[4][2], bool swap) {
  if (swap) {
#pragma unroll
    for (int mt = 0; mt < 4; ++mt)
#pragma unroll
      for (int nt = 0; nt < 2; ++nt)
        acc[mt][nt] = mfma16(bb[nt], a[mt], acc[mt][nt]);
  } else {
#pragma unroll
    for (int mt = 0; mt < 4; ++mt)
#pragma unroll
      for (int nt = 0; nt < 2; ++nt)
        acc[mt][nt] = mfma16(a[mt], bb[nt], acc[mt][nt]);
  }
}

__global__ __launch_bounds__(256) void gemm_qkv_kernel(
    const unsigned short* __restrict__ Wp, const float* __restrict__ bias,
    const unsigned short* __restrict__ Bp,
    unsigned short* __restrict__ Qp, unsigned short* __restrict__ Kp,
    unsigned short* __restrict__ Vp) {
  const int bid = blockIdx.x;
  const int swz = (bid & 7) * 96 + (bid >> 3);
  const int b = swz / 96, rr = swz % 96;
  const int mb = rr >> 4, nb = rr & 15;
  const int t = threadIdx.x;
  const int wave = t >> 6, lane = t & 63;
  const int li = lane & 15, grp = lane >> 4;
  const int m0 = mb * 128 + (wave >> 1) * 64;
  const int n0 = nb * 64 + (wave & 1) * 32;
  const bool swap = mb >= 4;   // V tiles
  const int Mt0 = m0 >> 4;
  const int Nt0 = b * 64 + (n0 >> 4);
  const s16x8* __restrict__ Af = (const s16x8*)Wp;
  const s16x8* __restrict__ Bf = (const s16x8*)Bp;

  f32x4 acc[4][2];
#pragma unroll
  for (int mt = 0; mt < 4; ++mt)
#pragma unroll
    for (int nt = 0; nt < 2; ++nt) acc[mt][nt] = f32x4{0.f, 0.f, 0.f, 0.f};

  s16x8 sa[3][4], sb[3][2];   // 3 rotating slots, depth-2 prefetch
  gload(Af, Bf, Mt0, Nt0, 0, lane, sa[0], sb[0]);
  gload(Af, Bf, Mt0, Nt0, 1, lane, sa[1], sb[1]);
#pragma unroll
  for (int kt = 0; kt < 8; ++kt) {
    if (kt + 2 < 8)
      gload(Af, Bf, Mt0, Nt0, kt + 2, lane, sa[(kt + 2) % 3], sb[(kt + 2) % 3]);
    gmfma(sa[kt % 3], sb[kt % 3], acc, swap);
  }

  if (!swap) {
    // Q/K: D rows = ch (4grp+r), cols = pos (li). Q gets kQScale folded in.
    unsigned short* __restrict__ Tp = (mb < 2) ? Qp : Kp;
    const float qs = (mb < 2) ? kQScale : 1.0f;
#pragma unroll
    for (int mt = 0; mt < 4; ++mt) {
      const int mbase = m0 + mt * 16;
      const int head = (mbase >> 6) & 3;
      const int bh = b * 4 + head;
      const int c16 = mbase & 63;
      const int ks = c16 >> 5;
      const int grpp = ((c16 >> 3) + (grp >> 1)) & 3;
      const float4 bv = *(const float4*)(bias + mbase + 4 * grp);
#pragma unroll
      for (int nt = 0; nt < 2; ++nt) {
        const int pt = (n0 >> 4) + nt;
        ushort4 o;
        o.x = f2bf((acc[mt][nt][0] + bv.x) * qs);
        o.y = f2bf((acc[mt][nt][1] + bv.y) * qs);
        o.z = f2bf((acc[mt][nt][2] + bv.z) * qs);
        o.w = f2bf((acc[mt][nt][3] + bv.w) * qs);
        *(ushort4*)(Tp + (size_t)bh * 65536 +
                    ((size_t)(pt * 2 + ks) * 64 + grpp * 16 + li) * 8 +
                    (grp & 1) * 4) = o;
      }
    }
  } else {
    // V: D rows = pos (4grp+r), cols = ch (li); sigma-permuted column store.
#pragma unroll
    for (int mt = 0; mt < 4; ++mt) {
      const int mbase = m0 + mt * 16;
      const int head = (mbase >> 6) & 3;
      const int bh = b * 4 + head;
      const int ct = (mbase & 63) >> 4;
      const float bvc = bias[mbase + li];
      const int kvt = n0 >> 5;
#pragma unroll
      for (int nt = 0; nt < 2; ++nt) {
        ushort4 o;
        o.x = f2bf(acc[mt][nt][0] + bvc);
        o.y = f2bf(acc[mt][nt][1] + bvc);
        o.z = f2bf(acc[mt][nt][2] + bvc);
        o.w = f2bf(acc[mt][nt][3] + bvc);
        *(ushort4*)(Vp + (size_t)bh * 65536 +
                    ((size_t)(ct * 32 + kvt) * 64 + grp * 16 + li) * 8 +
                    nt * 4) = o;
      }
    }
  }
}

// ---------------------------------------------------------------------------
// Fused flash-attention + proj. 256 blocks x 512 threads.
// Block = (b, 32 positions); 8 waves = 4 heads x 2 q-halves. P never touches
// LDS: sigma-permuted V makes the cvt_pk register pairs directly the PV
// B-frag. O exchanged via LDS proj-B-frags, then 32x32 proj tiles per wave.
// ---------------------------------------------------------------------------
__global__ __launch_bounds__(512) void attn_proj_kernel(
    const unsigned short* __restrict__ Qp, const unsigned short* __restrict__ Kp,
    const unsigned short* __restrict__ Vp, const unsigned short* __restrict__ Wpp,
    const float* __restrict__ bpj, const float* __restrict__ x,
    float* __restrict__ out) {
  __shared__ __align__(16) unsigned short Ex[2][8][64][8];   // proj B-frags, 16 KB
  const int bid = blockIdx.x;
  const int swz = (bid & 7) * 32 + (bid >> 3);   // 256 = 8*32, bijective
  const int b = swz >> 5, qb = swz & 31;         // batch = XCD; qb: 32-pos block
  const int t = threadIdx.x;
  const int w8 = t >> 6, lane = t & 63;
  const int head = w8 & 3, qh = w8 >> 2;
  const int li = lane & 15, grp = lane >> 4;
  const int q0 = qb * 32 + qh * 16;
  const int bh = b * 4 + head;
  const unsigned short* __restrict__ Qb = Qp + (size_t)bh * 65536;
  const unsigned short* __restrict__ Kb = Kp + (size_t)bh * 65536;
  const unsigned short* __restrict__ Vb = Vp + (size_t)bh * 65536;

  s16x8 qf[2];
#pragma unroll
  for (int ks = 0; ks < 2; ++ks)
    qf[ks] = *(const s16x8*)(Qb + (((q0 >> 4) * 2 + ks) * 64 + lane) * 8);

  f32x4 O[4];
#pragma unroll
  for (int ct = 0; ct < 4; ++ct) O[ct] = f32x4{0.f, 0.f, 0.f, 0.f};
  f32x4 lvec = f32x4{0.f, 0.f, 0.f, 0.f};
  float m_run = -1.0e30f;

  auto loadK = [&](int it, s16x8 (&kk)[2][2]) {
#pragma unroll
    for (int mt = 0; mt < 2; ++mt)
#pragma unroll
      for (int ks = 0; ks < 2; ++ks)
        kk[mt][ks] = *(const s16x8*)(
            Kb + ((size_t)((it * 2 + mt) * 2 + ks) * 64 + lane) * 8);
  };
  auto loadV = [&](int it, s16x8 (&vv)[4]) {
#pragma unroll
    for (int ct = 0; ct < 4; ++ct)
      vv[ct] = *(const s16x8*)(Vb + ((size_t)(ct * 32 + it) * 64 + lane) * 8);
  };
  auto qkt = [&](const s16x8 (&kk)[2][2], f32x4 (&s)[2]) {
#pragma unroll
    for (int mt = 0; mt < 2; ++mt) {
      s[mt] = mfma16(kk[mt][0], qf[0], f32x4{0.f, 0.f, 0.f, 0.f});
      s[mt] = mfma16(kk[mt][1], qf[1], s[mt]);
    }
  };
  // softmax(s) + in-register P pack (sigma layout) + PV-accumulate
  auto smaxpv = [&](f32x4 (&s)[2], const s16x8 (&vv)[4]) {
    const float A = fmaxf(fmaxf(s[0][0], s[0][1]), s[0][2]);
    const float B = fmaxf(fmaxf(s[0][3], s[1][0]), s[1][1]);
    const float C = fmaxf(fmaxf(s[1][2], s[1][3]), A);
    float pm = fmaxf(B, C);
    pm = fmaxf(pm, __shfl_xor(pm, 16));
    pm = fmaxf(pm, __shfl_xor(pm, 32));
    if (!__all(pm <= m_run + 8.0f)) {   // defer-max rescale (exp2 units)
      const float mnew = fmaxf(m_run, pm);
      const float f = exp2_fast(m_run - mnew);
      m_run = mnew;
      lvec *= f;
#pragma unroll
      for (int ct = 0; ct < 4; ++ct) O[ct] *= f;
    }
    f32x4 p[2];
#pragma unroll
    for (int mt = 0; mt < 2; ++mt) {
#pragma unroll
      for (int r = 0; r < 4; ++r) p[mt][r] = exp2_fast(s[mt][r] - m_run);
      lvec += p[mt];
    }
    // P -> bf16 B-frag entirely in registers (sigma-permuted V makes the
    // slot order [p00 p01 p02 p03 p10 p11 p12 p13] the correct k-order).
    u32x4 pk;
    pk[0] = cvt_pk_bf16(p[0][0], p[0][1]);
    pk[1] = cvt_pk_bf16(p[0][2], p[0][3]);
    pk[2] = cvt_pk_bf16(p[1][0], p[1][1]);
    pk[3] = cvt_pk_bf16(p[1][2], p[1][3]);
    const s16x8 pf = __builtin_bit_cast(s16x8, pk);
#pragma unroll
    for (int ct = 0; ct < 4; ++ct) O[ct] = mfma16(vv[ct], pf, O[ct]);
  };

  s16x8 k0[2][2], k1[2][2], v0[4], v1[4];
  loadK(0, k0);
  loadV(0, v0);
  f32x4 sc[2];
  qkt(k0, sc);        // S(0)
  loadK(1, k1);

  // Tail iterations overread K(33)/V(32) into adjacent ws regions (allocated;
  // values computed but never used) — keeps the loop branchless.
#pragma unroll 1
  for (int h2 = 0; h2 < 16; ++h2) {
    const int tt = 2 * h2;
    loadV(tt + 1, v1);
    f32x4 sn[2];
    qkt(k1, sn);            // S(tt+1)
    loadK(tt + 2, k0);
    smaxpv(sc, v0);         // finish tile tt
    loadV(tt + 2, v0);
    f32x4 s2[2];
    qkt(k0, s2);            // S(tt+2)
    loadK(tt + 3, k1);
    smaxpv(sn, v1);         // finish tile tt+1
    sc[0] = s2[0];
    sc[1] = s2[1];
  }

  float lt = lvec[0] + lvec[1] + lvec[2] + lvec[3];
  lt += __shfl_xor(lt, 16);
  lt += __shfl_xor(lt, 32);
  const float rinv = 1.f / lt;
  // O -> LDS proj-B-frags: q = q0+li (local pos-tile qh), c = head*64+ct*16+4grp+r
#pragma unroll
  for (int ct = 0; ct < 4; ++ct) {
    const int ktp = head * 2 + (ct >> 1);
    const int grpp = ((ct & 1) * 2 + (grp >> 1)) & 3;
    ushort4 o;
    o.x = f2bf(O[ct][0] * rinv);
    o.y = f2bf(O[ct][1] * rinv);
    o.z = f2bf(O[ct][2] * rinv);
    o.w = f2bf(O[ct][3] * rinv);
    *(ushort4*)&Ex[qh][ktp][grpp * 16 + li][(grp & 1) * 4] = o;
  }
  __syncthreads();

  // ---- proj: wave w8 computes out rows m0 = w8*32 .. +31, 32 positions ----
  {
    const int Mt0 = w8 * 2;
    const s16x8* __restrict__ Af = (const s16x8*)Wpp;
    f32x4 acc[2][2];
#pragma unroll
    for (int mt = 0; mt < 2; ++mt)
#pragma unroll
      for (int nt = 0; nt < 2; ++nt) acc[mt][nt] = f32x4{0.f, 0.f, 0.f, 0.f};

    s16x8 pa[3][2];
    auto loadA = [&](int kt, s16x8 (&a)[2]) {
#pragma unroll
      for (int mt = 0; mt < 2; ++mt)
        a[mt] = Af[((size_t)(Mt0 + mt) * 8 + kt) * 64 + lane];
    };
    loadA(0, pa[0]);
    loadA(1, pa[1]);
#pragma unroll
    for (int kt = 0; kt < 8; ++kt) {
      if (kt + 2 < 8) loadA(kt + 2, pa[(kt + 2) % 3]);
      s16x8 bb[2];
#pragma unroll
      for (int nt = 0; nt < 2; ++nt)
        bb[nt] = *(const s16x8*)&Ex[nt][kt][lane][0];
#pragma unroll
      for (int mt = 0; mt < 2; ++mt)
#pragma unroll
        for (int nt = 0; nt < 2; ++nt)
          acc[mt][nt] = mfma16(pa[kt % 3][mt], bb[nt], acc[mt][nt]);
    }

#pragma unroll
    for (int mt = 0; mt < 2; ++mt) {
      const int mbase = w8 * 32 + mt * 16 + 4 * grp;
      const float4 bv = *(const float4*)(bpj + mbase);
      const float bvr[4] = {bv.x, bv.y, bv.z, bv.w};
#pragma unroll
      for (int nt = 0; nt < 2; ++nt) {
        const int pos = qb * 32 + nt * 16 + li;
#pragma unroll
        for (int r2 = 0; r2 < 4; ++r2) {
          const size_t ob = ((size_t)(b * 256 + mbase + r2)) * 1024 + pos;
          out[ob] = acc[mt][nt][r2] + bvr[r2] + x[ob];
        }
      }
    }
  }
}

// ---------------------------------------------------------------------------
extern "C" void kernel_launch(void* const* d_in, const int* in_sizes, int n_in,
                              void* d_out, int out_size, void* d_ws, size_t ws_size,
                              hipStream_t stream) {
  const float* x      = (const float*)d_in[0];
  const float* gamma  = (const float*)d_in[1];
  const float* beta   = (const float*)d_in[2];
  const float* w_qkv  = (const float*)d_in[3];
  const float* b_qkv  = (const float*)d_in[4];
  const float* w_proj = (const float*)d_in[5];
  const float* b_proj = (const float*)d_in[6];
  float* out = (float*)d_out;

  unsigned short* ws = (unsigned short*)d_ws;
  unsigned short* Wqp  = ws;                    // 196608
  unsigned short* Wpp  = Wqp + 196608;          // 65536
  unsigned short* hTp  = Wpp + 65536;           // 2097152
  unsigned short* Qp   = hTp + 2097152;         // 2097152
  unsigned short* Kp   = Qp + 2097152;          // 2097152
  unsigned short* Vp   = Kp + 2097152;          // 2097152 (+2MB slack for overreads)

  hipLaunchKernelGGL(prep_kernel, dim3(384), dim3(256), 0, stream,
                     x, gamma, beta, hTp, w_qkv, w_proj, Wqp, Wpp);
  hipLaunchKernelGGL(gemm_qkv_kernel, dim3(768), dim3(256), 0, stream,
                     Wqp, b_qkv, hTp, Qp, Kp, Vp);
  hipLaunchKernelGGL(attn_proj_kernel, dim3(256), dim3(512), 0, stream,
                     Qp, Kp, Vp, Wpp, b_proj, x, out);
}